// Round 7
// baseline (244.141 us; speedup 1.0000x reference)
//
#include <hip/hip_runtime.h>
#include <stdint.h>

// Problem constants (MultiHeadAttention: S=2048, B=2, D=1024, H=16, Hd=64)
#define S_LEN 2048
#define BATCH 2
#define DM    1024
#define NH    16
#define HD    64
#define MROWS 4096            // GEMM rows, r = s*2 + b

typedef float f32x4 __attribute__((ext_vector_type(4)));
typedef short bfrag __attribute__((ext_vector_type(8)));   // 8 bf16 bit patterns (4 VGPRs)
typedef unsigned short u16x4_t __attribute__((ext_vector_type(4)));
typedef unsigned short u16x8_t __attribute__((ext_vector_type(8)));
typedef int i32x4_t __attribute__((ext_vector_type(4)));

#define EXP2F(x) __builtin_amdgcn_exp2f(x)

__device__ inline f32x4 mfma16(bfrag a, bfrag b, f32x4 c) {
    return __builtin_amdgcn_mfma_f32_16x16x32_bf16(a, b, c, 0, 0, 0);
}

// round-to-nearest-even-ish f32 -> bf16 bits
__device__ inline unsigned short bf16_rn(float x) {
    unsigned u = __builtin_bit_cast(unsigned, x);
    return (unsigned short)((u + 0x7fffu + ((u >> 16) & 1u)) >> 16);
}

// truncating hi/lo split: x ~= hi + lo with ~17 mantissa bits captured
__device__ inline void split_bf16(float x, unsigned short &h, unsigned short &l) {
    unsigned u = __builtin_bit_cast(unsigned, x);
    h = (unsigned short)(u >> 16);
    float hf = __builtin_bit_cast(float, u & 0xffff0000u);
    float r = x - hf;
    l = (unsigned short)(__builtin_bit_cast(unsigned, r) >> 16);
}

// pack two fp32 into one b32 of 2x bf16 via HW cvt (RNE): lo -> [15:0], hi -> [31:16]
__device__ inline unsigned cvtpk_bf16(float lo, float hi) {
    unsigned r;
    asm("v_cvt_pk_bf16_f32 %0, %1, %2" : "=v"(r) : "v"(lo), "v"(hi));
    return r;
}

// cross-lane half swaps (both operands updated):
// pl32: a' = {a[0:31], b[0:31]}, b' = {a[32:63], b[32:63]}
__device__ inline void pl32swap(unsigned &a, unsigned &b) {
    asm("v_permlane32_swap_b32 %0, %1" : "+v"(a), "+v"(b));
}
// pl16: a' = {a[0:15], b[0:15], a[32:47], b[32:47]},
//       b' = {a[16:31], b[16:31], a[48:63], b[48:63]}
__device__ inline void pl16swap(unsigned &a, unsigned &b) {
    asm("v_permlane16_swap_b32 %0, %1" : "+v"(a), "+v"(b));
}

// async global->LDS, 16B per lane; lds must be wave-uniform base (lane*16 implicit)
typedef __attribute__((address_space(1))) const unsigned int as1_u32;
typedef __attribute__((address_space(3))) unsigned int as3_u32;
__device__ inline void async16(void* lds, const void* g) {
    __builtin_amdgcn_global_load_lds((as1_u32*)g, (as3_u32*)lds, 16, 0, 0);
}

// ---------------------------------------------------------------------------
// Conversion pass: z=0..2 Wq/Wk/Wv -> bf16; z=3 Wo -> hi/lo planes;
// z=4..6 query/key/value -> bf16 A-planes. (unchanged, R1)
// ---------------------------------------------------------------------------
__global__ __launch_bounds__(256)
void cvt_kernel(const float* __restrict__ Wq, const float* __restrict__ Wk,
                const float* __restrict__ Wv, const float* __restrict__ Wo,
                const float* __restrict__ Qin, const float* __restrict__ Kin,
                const float* __restrict__ Vin,
                unsigned short* __restrict__ Wqb, unsigned short* __restrict__ Wkb,
                unsigned short* __restrict__ Wvb,
                unsigned short* __restrict__ Woh, unsigned short* __restrict__ Wol,
                unsigned short* __restrict__ Qa,  unsigned short* __restrict__ Ka,
                unsigned short* __restrict__ Va)
{
    const int z = blockIdx.z;
    size_t idx = ((size_t)blockIdx.x * 256 + threadIdx.x) * 8;
    const size_t limit = (z < 4) ? (size_t)DM * DM : (size_t)MROWS * DM;
    if (idx >= limit) return;
    const float* src = (z == 0) ? Wq : (z == 1) ? Wk : (z == 2) ? Wv :
                       (z == 3) ? Wo : (z == 4) ? Qin : (z == 5) ? Kin : Vin;
    float4 f0 = *(const float4*)&src[idx];
    float4 f1 = *(const float4*)&src[idx + 4];
    if (z != 3) {
        unsigned short* dst = (z == 0) ? Wqb : (z == 1) ? Wkb : (z == 2) ? Wvb :
                              (z == 4) ? Qa  : (z == 5) ? Ka  : Va;
        u16x8_t v = { bf16_rn(f0.x), bf16_rn(f0.y), bf16_rn(f0.z), bf16_rn(f0.w),
                      bf16_rn(f1.x), bf16_rn(f1.y), bf16_rn(f1.z), bf16_rn(f1.w) };
        *(u16x8_t*)&dst[idx] = v;
    } else {
        unsigned short h0,h1,h2,h3,h4,h5,h6,h7, l0,l1,l2,l3,l4,l5,l6,l7;
        split_bf16(f0.x,h0,l0); split_bf16(f0.y,h1,l1);
        split_bf16(f0.z,h2,l2); split_bf16(f0.w,h3,l3);
        split_bf16(f1.x,h4,l4); split_bf16(f1.y,h5,l5);
        split_bf16(f1.z,h6,l6); split_bf16(f1.w,h7,l7);
        u16x8_t vh = {h0,h1,h2,h3,h4,h5,h6,h7};
        u16x8_t vl = {l0,l1,l2,l3,l4,l5,l6,l7};
        *(u16x8_t*)&Woh[idx] = vh;
        *(u16x8_t*)&Wol[idx] = vl;
    }
}

// ---------------------------------------------------------------------------
// Q/K/V projection — EXACT R1 structure (single-buffered BK=32, proven best
// total). R5/R6 ledger: BK64 single 61us, BK32 dbuf 50us, BK32 single <=47.7:
// both "improvements" regressed vs this shape at K=1024. Do not touch.
// ---------------------------------------------------------------------------
__global__ __launch_bounds__(256)
void qkv_gemm(const unsigned short* __restrict__ Qa,
              const unsigned short* __restrict__ Ka,
              const unsigned short* __restrict__ Va,
              const unsigned short* __restrict__ Wqb,
              const unsigned short* __restrict__ Wkb,
              const unsigned short* __restrict__ Wvb,
              const float* __restrict__ bq, const float* __restrict__ bk,
              const float* __restrict__ bv,
              unsigned short* __restrict__ Qb, unsigned short* __restrict__ Kb,
              unsigned short* __restrict__ Vt)
{
    __shared__ unsigned short sA[128*32];   // 8 KB bf16 A tile
    __shared__ unsigned short sB[128*32];   // 8 KB bf16 W tile

    const int tid = threadIdx.x, lane = tid & 63, w4 = tid >> 6;
    const int m16 = lane & 15, q4 = lane >> 4;
    const int wr = w4 >> 1, wc = w4 & 1;   // 2x2 wave grid -> 64x64 per wave
    const int z = blockIdx.z;

    int id = blockIdx.x + 8 * blockIdx.y;
    int j  = id >> 3;
    const int m0 = ((id & 7) * 4 + (j & 3)) * 128;
    const int n0 = (j >> 2) * 128;

    const unsigned short* A = (z == 0) ? Qa : (z == 1) ? Ka : Va;
    const unsigned short* W = (z == 0) ? Wqb : (z == 1) ? Wkb : Wvb;
    const float* bias = (z == 0) ? bq : (z == 1) ? bk : bv;
    unsigned short* outp = (z == 0) ? Qb : (z == 1) ? Kb : Vt;

    const int G1 = tid + 256;
    const int r0 = tid >> 2, g0 = (tid & 3) ^ ((r0 ^ (r0 >> 2)) & 3);
    const int r1 = G1  >> 2, g1 = (G1  & 3) ^ ((r1 ^ (r1 >> 2)) & 3);
    const char* gA0 = (const char*)A + (size_t)(m0 + r0) * 2048 + g0 * 16;
    const char* gA1 = (const char*)A + (size_t)(m0 + r1) * 2048 + g1 * 16;
    const char* gB0 = (const char*)W + (size_t)(n0 + r0) * 2048 + g0 * 16;
    const char* gB1 = (const char*)W + (size_t)(n0 + r1) * 2048 + g1 * 16;
    char* ldsA0 = (char*)sA + w4 * 1024;
    char* ldsA1 = (char*)sA + 4096 + w4 * 1024;
    char* ldsB0 = (char*)sB + w4 * 1024;
    char* ldsB1 = (char*)sB + 4096 + w4 * 1024;

    int offA[4], offB[4];
    #pragma unroll
    for (int rt = 0; rt < 4; rt++) {
        int r = wr * 64 + rt * 16 + m16;
        offA[rt] = r * 32 + ((q4 ^ ((r ^ (r >> 2)) & 3)) << 3);
    }
    #pragma unroll
    for (int ct = 0; ct < 4; ct++) {
        int r = wc * 64 + ct * 16 + m16;
        offB[ct] = r * 32 + ((q4 ^ ((r ^ (r >> 2)) & 3)) << 3);
    }

    f32x4 acc[4][4];
    const f32x4 zero4 = {0.f, 0.f, 0.f, 0.f};
    #pragma unroll
    for (int i = 0; i < 4; i++)
        #pragma unroll
        for (int jj = 0; jj < 4; jj++) acc[i][jj] = zero4;

    for (int k0 = 0; k0 < DM; k0 += 32) {
        async16(ldsA0, gA0);
        async16(ldsA1, gA1);
        async16(ldsB0, gB0);
        async16(ldsB1, gB1);
        gA0 += 64; gA1 += 64; gB0 += 64; gB1 += 64;
        __syncthreads();

        bfrag a[4], bb[4];
        #pragma unroll
        for (int rt = 0; rt < 4; rt++) a[rt]  = *(const bfrag*)&sA[offA[rt]];
        #pragma unroll
        for (int ct = 0; ct < 4; ct++) bb[ct] = *(const bfrag*)&sB[offB[ct]];

        #pragma unroll
        for (int rt = 0; rt < 4; rt++)
            #pragma unroll
            for (int ct = 0; ct < 4; ct++)
                acc[rt][ct] = mfma16(a[rt], bb[ct], acc[rt][ct]);
        __syncthreads();
    }

    const float SCALE = (z == 0) ? 0.18033688011112042f : 1.0f; // log2(e)/8
    #pragma unroll
    for (int rt = 0; rt < 4; rt++)
        #pragma unroll
        for (int ct = 0; ct < 4; ct++)
            #pragma unroll
            for (int reg = 0; reg < 4; reg++) {
                int r = m0 + wr * 64 + rt * 16 + q4 * 4 + reg;
                int c = n0 + wc * 64 + ct * 16 + m16;
                float v = (acc[rt][ct][reg] + bias[c]) * SCALE;
                int s = r >> 1, b = r & 1, hh = c >> 6, d = c & 63;
                unsigned short bv16 = bf16_rn(v);
                if (z == 2)
                    outp[((size_t)(b * NH + hh) * HD + d) * S_LEN + s] = bv16;
                else
                    outp[((size_t)(b * NH + hh) * S_LEN + s) * HD + d] = bv16;
            }
}

// ---------------------------------------------------------------------------
// Attention, t-split x2 — EXACT R1 structure (proven 47.7 us, 0 conflicts,
// 64 VGPR, no spill). Ledger: setprio +15us (R4), frag-hoist spills (R3),
// t-split x4 thrashes L2 writes (R2). Local optimum; unchanged.
// Op partials now land in ws (not d_out) so the fused out_gemm can read them
// while writing d_out without a race.
// ---------------------------------------------------------------------------
__global__ __launch_bounds__(256, 4)
void attn_kernel(const unsigned short* __restrict__ Qb,
                 const unsigned short* __restrict__ Kb,
                 const unsigned short* __restrict__ Vt,
                 unsigned short* __restrict__ Op,   // [2][BATCH*NH][S][HD] bf16
                 float* __restrict__ Lp)            // [2][BATCH*NH*S] fp32
{
    __shared__ unsigned short sK[2][64*64];    // 2 x 8 KB, XOR-swizzled rows
    __shared__ unsigned short sV[2][64*64];    // 2 x 8 KB

    const int tid = threadIdx.x, lane = tid & 63, w4 = tid >> 6;
    const int m16 = lane & 15, q4 = lane >> 4;

    int id = blockIdx.x;                 // 0..1023
    int xcd = id & 7, j = id >> 3;       // j 0..127
    const int bh   = xcd * 4 + (j >> 5); // 4 heads per XCD
    const int rem  = j & 31;
    const int half = rem & 1;            // t-range half
    const int qc   = rem >> 1;           // 0..15
    const int qw   = qc * 128 + w4 * 32;
    const int tbase = half * (S_LEN / 2);

    const unsigned short* Qp = Qb + (size_t)bh * (S_LEN * HD);
    const unsigned short* Kp = Kb + (size_t)bh * (S_LEN * HD);
    const unsigned short* Vp = Vt + (size_t)bh * (S_LEN * HD);

    // Q B-fragments (fixed for whole kernel): [n=q=lane&15][k=d]
    bfrag aq[2][2];
    #pragma unroll
    for (int nt = 0; nt < 2; nt++)
        #pragma unroll
        for (int kc = 0; kc < 2; kc++)
            aq[nt][kc] = *(const bfrag*)&Qp[(size_t)(qw + nt*16 + m16) * HD + kc*32 + q4*8];

    // staging: 512 granules (16B) per matrix, 2 async16 per thread per matrix.
    const int r0 = tid >> 3,         g0 = (tid & 7) ^ (r0 & 7);
    const int r1 = (tid + 256) >> 3, g1 = (tid & 7) ^ (r1 & 7);
    const char* gK0 = (const char*)Kp + (size_t)(tbase + r0) * 128 + g0 * 16;
    const char* gK1 = (const char*)Kp + (size_t)(tbase + r1) * 128 + g1 * 16;
    const char* gV0 = (const char*)Vp + (size_t)r0 * 4096 + tbase * 2 + g0 * 16;
    const char* gV1 = (const char*)Vp + (size_t)r1 * 4096 + tbase * 2 + g1 * 16;
    const int ldsw = w4 * 1024;

    const f32x4 zero4 = {0.f, 0.f, 0.f, 0.f};
    f32x4 O[2][4];
    float lp[2] = {0.f, 0.f};
    #pragma unroll
    for (int nt = 0; nt < 2; nt++)
        #pragma unroll
        for (int dt = 0; dt < 4; dt++) O[nt][dt] = zero4;

    // prefetch tile 0 into buffer 0
    async16((char*)sK[0] + ldsw,        gK0);
    async16((char*)sK[0] + 4096 + ldsw, gK1);
    async16((char*)sV[0] + ldsw,        gV0);
    async16((char*)sV[0] + 4096 + ldsw, gV1);

    const int NT = (S_LEN / 2) / 64;     // 16 tiles per half
    for (int it = 0; it < NT; it++) {
        const int bi = it & 1;
        __syncthreads();   // drains async (cur tile ready) + prior compute done
        if (it + 1 < NT) {
            size_t ko = (size_t)(it + 1) * 8192, vo = (size_t)(it + 1) * 128;
            async16((char*)sK[bi^1] + ldsw,        gK0 + ko);
            async16((char*)sK[bi^1] + 4096 + ldsw, gK1 + ko);
            async16((char*)sV[bi^1] + ldsw,        gV0 + vo);
            async16((char*)sV[bi^1] + 4096 + ldsw, gV1 + vo);
        }

        const unsigned short* kb = sK[bi];
        const unsigned short* vb = sV[bi];

        // K A-frags [m=t][k=d] from swizzled LDS
        bfrag ak[4][2];
        #pragma unroll
        for (int mt = 0; mt < 4; mt++) {
            int r = mt*16 + m16, s = r & 7;
            ak[mt][0] = *(const bfrag*)&kb[r*64 + ((q4     ^ s) << 3)];
            ak[mt][1] = *(const bfrag*)&kb[r*64 + (((4+q4) ^ s) << 3)];
        }

        // S^T = K.Q^T; p = exp2(s); cvt_pk to bf16 pairs; permlane-swap into
        // PV B-frags entirely in-register. l from raw p (additive).
        bfrag bpv[2][2];
        #pragma unroll
        for (int nt = 0; nt < 2; nt++) {
            f32x4 Sc[4];
            #pragma unroll
            for (int mt = 0; mt < 4; mt++) {
                Sc[mt] = mfma16(ak[mt][0], aq[nt][0], zero4);
                Sc[mt] = mfma16(ak[mt][1], aq[nt][1], Sc[mt]);
            }
            unsigned u0[4], u1[4];
            #pragma unroll
            for (int mt = 0; mt < 4; mt++) {
                float p0 = EXP2F(Sc[mt][0]), p1 = EXP2F(Sc[mt][1]);
                float p2 = EXP2F(Sc[mt][2]), p3 = EXP2F(Sc[mt][3]);
                lp[nt] += (p0 + p1) + (p2 + p3);
                u0[mt] = cvtpk_bf16(p0, p1);   // t = base+{0,1}
                u1[mt] = cvtpk_bf16(p2, p3);   // t = base+{2,3}
            }
            #pragma unroll
            for (int kc = 0; kc < 2; kc++) {
                unsigned a0 = u0[2*kc], b0 = u0[2*kc+1];
                pl32swap(a0, b0);              // bit5 exchange (tile select)
                pl16swap(a0, b0);              // bit4 exchange -> a0: j2=0, b0: j2=2
                unsigned a1 = u1[2*kc], b1 = u1[2*kc+1];
                pl32swap(a1, b1);
                pl16swap(a1, b1);              // a1: j2=1, b1: j2=3
                i32x4_t w = { (int)a0, (int)a1, (int)b0, (int)b1 };
                bpv[nt][kc] = __builtin_bit_cast(bfrag, w);
            }
        }

        // V^T A-frags [m=d][k=t] from swizzled LDS
        bfrag av[4][2];
        #pragma unroll
        for (int dt = 0; dt < 4; dt++) {
            int r = dt*16 + m16, s = r & 7;
            av[dt][0] = *(const bfrag*)&vb[r*64 + ((q4     ^ s) << 3)];
            av[dt][1] = *(const bfrag*)&vb[r*64 + (((4+q4) ^ s) << 3)];
        }

        // O^T += V^T . P^T  (P^T B-frags in registers)
        #pragma unroll
        for (int nt = 0; nt < 2; nt++)
            #pragma unroll
            for (int dt = 0; dt < 4; dt++) {
                O[nt][dt] = mfma16(av[dt][0], bpv[nt][0], O[nt][dt]);
                O[nt][dt] = mfma16(av[dt][1], bpv[nt][1], O[nt][dt]);
            }
    }

    // epilogue: reduce l over quads, write UNNORMALIZED bf16 O partial + l
    const size_t OPH = (size_t)BATCH * NH * S_LEN * HD;  // 4,194,304 elems
    unsigned short* Ob = Op + (size_t)half * OPH;
    float* Lb = Lp + (size_t)half * (BATCH * NH * S_LEN);
    #pragma unroll
    for (int nt = 0; nt < 2; nt++) {
        float l = lp[nt];
        l += __shfl_xor(l, 16);
        l += __shfl_xor(l, 32);
        int q = qw + nt*16 + m16;
        if (q4 == 0) Lb[(size_t)bh * S_LEN + q] = l;
        size_t rb = ((size_t)bh * S_LEN + q) * HD;
        #pragma unroll
        for (int dt = 0; dt < 4; dt++) {
            u16x4_t o = { bf16_rn(O[nt][dt][0]), bf16_rn(O[nt][dt][1]),
                          bf16_rn(O[nt][dt][2]), bf16_rn(O[nt][dt][3]) };
            *(u16x4_t*)&Ob[rb + dt*16 + q4*4] = o;
        }
    }
}

// ---------------------------------------------------------------------------
// Out projection FUSED with the partial-combine (cmb_kernel deleted; one
// launch + one 25 MB pass saved). A-staging maps tile (row r, cols k0+g*8)
// to Op: q=r>>1, b=r&1, h=k0>>6 (LANE-UNIFORM since (k0&63)+g*8 < 64),
// rho=(b*16+h)*2048+q; combine = bf16_rn((O0+O1)*inv) — bit-identical to
// cmb's math. ds_write_b128 to the same LDS slots async16 used (layout and
// swizzle unchanged; readers untouched). W path stays async16.
// ---------------------------------------------------------------------------
__global__ __launch_bounds__(256)
void out_gemm(const unsigned short* __restrict__ Op,   // [2][32][2048][64] bf16
              const float* __restrict__ Lp,            // [2][65536] fp32
              const unsigned short* __restrict__ Woh,
              const unsigned short* __restrict__ Wol,
              const float* __restrict__ bo, float* __restrict__ out)
{
    __shared__ unsigned short sA[128*32];   // 8 KB (combined A tile)
    __shared__ unsigned short sH[64*32];    // 4 KB
    __shared__ unsigned short sL[64*32];    // 4 KB

    const size_t OPH = (size_t)BATCH * NH * S_LEN * HD;  // elems per part
    const int BNS = BATCH * NH * S_LEN;                  // 65536

    const int tid = threadIdx.x, lane = tid & 63, w4 = tid >> 6;
    const int m16 = lane & 15, q4 = lane >> 4;
    const int wr = w4 >> 1, wc = w4 & 1;    // 2x2 -> 64 M x 32 N per wave

    int id = blockIdx.x + 16 * blockIdx.y;  // 512 blocks
    int j  = id >> 3;                        // 0..63
    const int m0 = ((id & 7) * 4 + (j & 3)) * 128;
    const int n0 = (j >> 2) * 64;

    // A staging rows/granules (same swizzle as R1): 512 granules, 2/thread.
    const int G1 = tid + 256;
    const int r0 = tid >> 2, g0 = (tid & 3) ^ ((r0 ^ (r0 >> 2)) & 3);
    const int r1 = G1  >> 2, g1 = (G1  & 3) ^ ((r1 ^ (r1 >> 2)) & 3);
    const int ra = m0 + r0, rb_ = m0 + r1;
    const int qa = ra >> 1,  ba = ra & 1;
    const int qb = rb_ >> 1, bb = rb_ & 1;
    const char* gH = (const char*)Woh + (size_t)(n0 + r0) * 2048 + g0 * 16;
    const char* gL = (const char*)Wol + (size_t)(n0 + r0) * 2048 + g0 * 16;
    char* ldsH = (char*)sH + w4 * 1024;
    char* ldsL = (char*)sL + w4 * 1024;
    // LDS dests matching async16's implicit base+lane*16 layout:
    unsigned short* dstA0 = (unsigned short*)((char*)sA + w4 * 1024 + lane * 16);
    unsigned short* dstA1 = (unsigned short*)((char*)sA + 4096 + w4 * 1024 + lane * 16);

    int offA[4], offB[2];
    #pragma unroll
    for (int rt = 0; rt < 4; rt++) {
        int r = wr * 64 + rt * 16 + m16;
        offA[rt] = r * 32 + ((q4 ^ ((r ^ (r >> 2)) & 3)) << 3);
    }
    #pragma unroll
    for (int ct = 0; ct < 2; ct++) {
        int r = wc * 32 + ct * 16 + m16;
        offB[ct] = r * 32 + ((q4 ^ ((r ^ (r >> 2)) & 3)) << 3);
    }

    f32x4 acc[4][2];
    const f32x4 zero4 = {0.f, 0.f, 0.f, 0.f};
    #pragma unroll
    for (int i = 0; i < 4; i++)
        #pragma unroll
        for (int jj = 0; jj < 2; jj++) acc[i][jj] = zero4;

    for (int k0 = 0; k0 < DM; k0 += 32) {
        // --- fused A staging: load partials, combine, write LDS ---
        const int h  = k0 >> 6;            // lane-uniform head index
        const int c0 = k0 & 63;            // 0 or 32
        const int rhoA = (ba * NH + h) * S_LEN + qa;
        const int rhoB = (bb * NH + h) * S_LEN + qb;
        size_t eA = (size_t)rhoA * HD + c0 + g0 * 8;
        size_t eB = (size_t)rhoB * HD + c0 + g1 * 8;
        u16x8_t a0 = *(const u16x8_t*)&Op[eA];
        u16x8_t a1 = *(const u16x8_t*)&Op[OPH + eA];
        u16x8_t b0 = *(const u16x8_t*)&Op[eB];
        u16x8_t b1 = *(const u16x8_t*)&Op[OPH + eB];
        // W staging via DMA (overlaps with combine below)
        async16(ldsH, gH);
        async16(ldsL, gL);
        gH += 64; gL += 64;
        float invA = 1.0f / (Lp[rhoA] + Lp[BNS + rhoA]);
        float invB = 1.0f / (Lp[rhoB] + Lp[BNS + rhoB]);
        u16x8_t va, vb;
        #pragma unroll
        for (int i = 0; i < 8; i++) {
            float fa0 = __builtin_bit_cast(float, (unsigned)a0[i] << 16);
            float fa1 = __builtin_bit_cast(float, (unsigned)a1[i] << 16);
            va[i] = bf16_rn((fa0 + fa1) * invA);
            float fb0 = __builtin_bit_cast(float, (unsigned)b0[i] << 16);
            float fb1 = __builtin_bit_cast(float, (unsigned)b1[i] << 16);
            vb[i] = bf16_rn((fb0 + fb1) * invB);
        }
        *(u16x8_t*)dstA0 = va;
        *(u16x8_t*)dstA1 = vb;
        __syncthreads();

        bfrag a[4], bh2[2], bl2[2];
        #pragma unroll
        for (int rt = 0; rt < 4; rt++) a[rt] = *(const bfrag*)&sA[offA[rt]];
        #pragma unroll
        for (int ct = 0; ct < 2; ct++) {
            bh2[ct] = *(const bfrag*)&sH[offB[ct]];
            bl2[ct] = *(const bfrag*)&sL[offB[ct]];
        }
        #pragma unroll
        for (int rt = 0; rt < 4; rt++)
            #pragma unroll
            for (int ct = 0; ct < 2; ct++) {
                acc[rt][ct] = mfma16(a[rt], bh2[ct], acc[rt][ct]);
                acc[rt][ct] = mfma16(a[rt], bl2[ct], acc[rt][ct]);
            }
        __syncthreads();
    }

    #pragma unroll
    for (int rt = 0; rt < 4; rt++)
        #pragma unroll
        for (int ct = 0; ct < 2; ct++)
            #pragma unroll
            for (int reg = 0; reg < 4; reg++) {
                int r = m0 + wr * 64 + rt * 16 + q4 * 4 + reg;
                int c = n0 + wc * 32 + ct * 16 + m16;
                out[(size_t)r * DM + c] = acc[rt][ct][reg] + bo[c];
            }
}

// ---------------------------------------------------------------------------
extern "C" void kernel_launch(void* const* d_in, const int* in_sizes, int n_in,
                              void* d_out, int out_size, void* d_ws, size_t ws_size,
                              hipStream_t stream)
{
    const float* query = (const float*)d_in[0];
    const float* key   = (const float*)d_in[1];
    const float* value = (const float*)d_in[2];
    const float* Wq    = (const float*)d_in[3];
    const float* bq    = (const float*)d_in[4];
    const float* Wk    = (const float*)d_in[5];
    const float* bk    = (const float*)d_in[6];
    const float* Wv    = (const float*)d_in[7];
    const float* bv    = (const float*)d_in[8];
    const float* Wo    = (const float*)d_in[9];
    const float* bo    = (const float*)d_in[10];

    char* ws = (char*)d_ws;
    const size_t MB = 1u << 20;
    unsigned short* Qb  = (unsigned short*)(ws);            //  0..8 MB
    unsigned short* Kb  = (unsigned short*)(ws +  8*MB);    //  8..16
    unsigned short* Vt  = (unsigned short*)(ws + 16*MB);    // 16..24
    unsigned short* Woh = (unsigned short*)(ws + 24*MB);    // 24..26 (live till out)
    unsigned short* Wol = (unsigned short*)(ws + 26*MB);    // 26..28
    unsigned short* Wqb = (unsigned short*)(ws + 28*MB);    // 28..30 (dead after qkv)
    unsigned short* Wkb = (unsigned short*)(ws + 30*MB);    // 30..32 (dead after qkv)
    unsigned short* Wvb = (unsigned short*)(ws + 32*MB);    // 32..34 (dead after qkv)
    unsigned short* Va  = (unsigned short*)(ws + 34*MB);    // 34..42 (dead after qkv)
    // attn-phase reuse (over regions dead after qkv):
    float*          Lp  = (float*)         (ws + 28*MB);          // 28..28.5 MB
    unsigned short* Opart = (unsigned short*)(ws + 28*MB + 512*1024); // 28.5..44.5 MB
    // (ws_size >= 46 MB verified: R2's TSPLIT=4 path ran and passed at 46 MB)
    // Qa/Ka bf16 A-planes live in d_out during cvt+qkv (d_out free till out_gemm).
    unsigned short* Qa  = (unsigned short*)d_out;                    // d_out 0..8 MB
    unsigned short* Ka  = (unsigned short*)d_out + (size_t)MROWS*DM; // 8..16 MB
    // peak ws footprint: 44.5 MB

    cvt_kernel<<<dim3(2048, 1, 7), 256, 0, stream>>>(
        Wq, Wk, Wv, Wo, query, key, value,
        Wqb, Wkb, Wvb, Woh, Wol, Qa, Ka, Va);
    qkv_gemm<<<dim3(8, 32, 3), 256, 0, stream>>>(
        Qa, Ka, Va, Wqb, Wkb, Wvb, bq, bk, bv, Qb, Kb, Vt);
    attn_kernel<<<dim3(1024), 256, 0, stream>>>(Qb, Kb, Vt, Opart, Lp);
    out_gemm<<<dim3(16, 32), 256, 0, stream>>>(
        Opart, Lp, Woh, Wol, bo, (float*)d_out);
}

// Round 8
// 223.160 us; speedup vs baseline: 1.0940x; 1.0940x over previous
//
#include <hip/hip_runtime.h>
#include <stdint.h>

// Problem constants (MultiHeadAttention: S=2048, B=2, D=1024, H=16, Hd=64)
#define S_LEN 2048
#define BATCH 2
#define DM    1024
#define NH    16
#define HD    64
#define MROWS 4096            // GEMM rows, r = s*2 + b

typedef float f32x4 __attribute__((ext_vector_type(4)));
typedef short bfrag __attribute__((ext_vector_type(8)));   // 8 bf16 bit patterns (4 VGPRs)
typedef unsigned short u16x4_t __attribute__((ext_vector_type(4)));
typedef unsigned short u16x8_t __attribute__((ext_vector_type(8)));
typedef unsigned int u32x4_t __attribute__((ext_vector_type(4)));
typedef int i32x4_t __attribute__((ext_vector_type(4)));

#define EXP2F(x) __builtin_amdgcn_exp2f(x)

__device__ inline f32x4 mfma16(bfrag a, bfrag b, f32x4 c) {
    return __builtin_amdgcn_mfma_f32_16x16x32_bf16(a, b, c, 0, 0, 0);
}

// round-to-nearest-even-ish f32 -> bf16 bits
__device__ inline unsigned short bf16_rn(float x) {
    unsigned u = __builtin_bit_cast(unsigned, x);
    return (unsigned short)((u + 0x7fffu + ((u >> 16) & 1u)) >> 16);
}

// truncating hi/lo split: x ~= hi + lo with ~17 mantissa bits captured
__device__ inline void split_bf16(float x, unsigned short &h, unsigned short &l) {
    unsigned u = __builtin_bit_cast(unsigned, x);
    h = (unsigned short)(u >> 16);
    float hf = __builtin_bit_cast(float, u & 0xffff0000u);
    float r = x - hf;
    l = (unsigned short)(__builtin_bit_cast(unsigned, r) >> 16);
}

// pack two fp32 into one b32 of 2x bf16 via HW cvt (RNE): lo -> [15:0], hi -> [31:16]
__device__ inline unsigned cvtpk_bf16(float lo, float hi) {
    unsigned r;
    asm("v_cvt_pk_bf16_f32 %0, %1, %2" : "=v"(r) : "v"(lo), "v"(hi));
    return r;
}

// cross-lane half swaps (both operands updated):
// pl32: a' = {a[0:31], b[0:31]}, b' = {a[32:63], b[32:63]}
__device__ inline void pl32swap(unsigned &a, unsigned &b) {
    asm("v_permlane32_swap_b32 %0, %1" : "+v"(a), "+v"(b));
}
// pl16: a' = {a[0:15], b[0:15], a[32:47], b[32:47]},
//       b' = {a[16:31], b[16:31], a[48:63], b[48:63]}
__device__ inline void pl16swap(unsigned &a, unsigned &b) {
    asm("v_permlane16_swap_b32 %0, %1" : "+v"(a), "+v"(b));
}

// async global->LDS, 16B per lane; lds must be wave-uniform base (lane*16 implicit)
typedef __attribute__((address_space(1))) const unsigned int as1_u32;
typedef __attribute__((address_space(3))) unsigned int as3_u32;
__device__ inline void async16(void* lds, const void* g) {
    __builtin_amdgcn_global_load_lds((as1_u32*)g, (as3_u32*)lds, 16, 0, 0);
}

// ---------------------------------------------------------------------------
// Conversion pass: z=0..2 Wq/Wk/Wv -> bf16; z=3 Wo -> hi/lo planes;
// z=4..6 query/key/value -> bf16 A-planes.
// R8: z!=3 path uses v_cvt_pk_bf16_f32 (4 instr vs 40 VALU ops/thread).
// RNE vs bf16_rn differs only on exact-tie low halves (p~2^-16) -> <=1e-4
// output shift through K=1024 dot products. z==3 keeps exact split_bf16.
// ---------------------------------------------------------------------------
__global__ __launch_bounds__(256)
void cvt_kernel(const float* __restrict__ Wq, const float* __restrict__ Wk,
                const float* __restrict__ Wv, const float* __restrict__ Wo,
                const float* __restrict__ Qin, const float* __restrict__ Kin,
                const float* __restrict__ Vin,
                unsigned short* __restrict__ Wqb, unsigned short* __restrict__ Wkb,
                unsigned short* __restrict__ Wvb,
                unsigned short* __restrict__ Woh, unsigned short* __restrict__ Wol,
                unsigned short* __restrict__ Qa,  unsigned short* __restrict__ Ka,
                unsigned short* __restrict__ Va)
{
    const int z = blockIdx.z;
    size_t idx = ((size_t)blockIdx.x * 256 + threadIdx.x) * 8;
    const size_t limit = (z < 4) ? (size_t)DM * DM : (size_t)MROWS * DM;
    if (idx >= limit) return;
    const float* src = (z == 0) ? Wq : (z == 1) ? Wk : (z == 2) ? Wv :
                       (z == 3) ? Wo : (z == 4) ? Qin : (z == 5) ? Kin : Vin;
    float4 f0 = *(const float4*)&src[idx];
    float4 f1 = *(const float4*)&src[idx + 4];
    if (z != 3) {
        unsigned short* dst = (z == 0) ? Wqb : (z == 1) ? Wkb : (z == 2) ? Wvb :
                              (z == 4) ? Qa  : (z == 5) ? Ka  : Va;
        u32x4_t v = { cvtpk_bf16(f0.x, f0.y), cvtpk_bf16(f0.z, f0.w),
                      cvtpk_bf16(f1.x, f1.y), cvtpk_bf16(f1.z, f1.w) };
        *(u32x4_t*)&dst[idx] = v;
    } else {
        unsigned short h0,h1,h2,h3,h4,h5,h6,h7, l0,l1,l2,l3,l4,l5,l6,l7;
        split_bf16(f0.x,h0,l0); split_bf16(f0.y,h1,l1);
        split_bf16(f0.z,h2,l2); split_bf16(f0.w,h3,l3);
        split_bf16(f1.x,h4,l4); split_bf16(f1.y,h5,l5);
        split_bf16(f1.z,h6,l6); split_bf16(f1.w,h7,l7);
        u16x8_t vh = {h0,h1,h2,h3,h4,h5,h6,h7};
        u16x8_t vl = {l0,l1,l2,l3,l4,l5,l6,l7};
        *(u16x8_t*)&Woh[idx] = vh;
        *(u16x8_t*)&Wol[idx] = vl;
    }
}

// ---------------------------------------------------------------------------
// Q/K/V projection — EXACT R1 structure (single-buffered BK=32). Ledger:
// BK64 single = 61us (R5), BK32 dbuf = 50us (R6), this = ~47.5. Do not touch.
// ---------------------------------------------------------------------------
__global__ __launch_bounds__(256)
void qkv_gemm(const unsigned short* __restrict__ Qa,
              const unsigned short* __restrict__ Ka,
              const unsigned short* __restrict__ Va,
              const unsigned short* __restrict__ Wqb,
              const unsigned short* __restrict__ Wkb,
              const unsigned short* __restrict__ Wvb,
              const float* __restrict__ bq, const float* __restrict__ bk,
              const float* __restrict__ bv,
              unsigned short* __restrict__ Qb, unsigned short* __restrict__ Kb,
              unsigned short* __restrict__ Vt)
{
    __shared__ unsigned short sA[128*32];   // 8 KB bf16 A tile
    __shared__ unsigned short sB[128*32];   // 8 KB bf16 W tile

    const int tid = threadIdx.x, lane = tid & 63, w4 = tid >> 6;
    const int m16 = lane & 15, q4 = lane >> 4;
    const int wr = w4 >> 1, wc = w4 & 1;   // 2x2 wave grid -> 64x64 per wave
    const int z = blockIdx.z;

    int id = blockIdx.x + 8 * blockIdx.y;
    int j  = id >> 3;
    const int m0 = ((id & 7) * 4 + (j & 3)) * 128;
    const int n0 = (j >> 2) * 128;

    const unsigned short* A = (z == 0) ? Qa : (z == 1) ? Ka : Va;
    const unsigned short* W = (z == 0) ? Wqb : (z == 1) ? Wkb : Wvb;
    const float* bias = (z == 0) ? bq : (z == 1) ? bk : bv;
    unsigned short* outp = (z == 0) ? Qb : (z == 1) ? Kb : Vt;

    const int G1 = tid + 256;
    const int r0 = tid >> 2, g0 = (tid & 3) ^ ((r0 ^ (r0 >> 2)) & 3);
    const int r1 = G1  >> 2, g1 = (G1  & 3) ^ ((r1 ^ (r1 >> 2)) & 3);
    const char* gA0 = (const char*)A + (size_t)(m0 + r0) * 2048 + g0 * 16;
    const char* gA1 = (const char*)A + (size_t)(m0 + r1) * 2048 + g1 * 16;
    const char* gB0 = (const char*)W + (size_t)(n0 + r0) * 2048 + g0 * 16;
    const char* gB1 = (const char*)W + (size_t)(n0 + r1) * 2048 + g1 * 16;
    char* ldsA0 = (char*)sA + w4 * 1024;
    char* ldsA1 = (char*)sA + 4096 + w4 * 1024;
    char* ldsB0 = (char*)sB + w4 * 1024;
    char* ldsB1 = (char*)sB + 4096 + w4 * 1024;

    int offA[4], offB[4];
    #pragma unroll
    for (int rt = 0; rt < 4; rt++) {
        int r = wr * 64 + rt * 16 + m16;
        offA[rt] = r * 32 + ((q4 ^ ((r ^ (r >> 2)) & 3)) << 3);
    }
    #pragma unroll
    for (int ct = 0; ct < 4; ct++) {
        int r = wc * 64 + ct * 16 + m16;
        offB[ct] = r * 32 + ((q4 ^ ((r ^ (r >> 2)) & 3)) << 3);
    }

    f32x4 acc[4][4];
    const f32x4 zero4 = {0.f, 0.f, 0.f, 0.f};
    #pragma unroll
    for (int i = 0; i < 4; i++)
        #pragma unroll
        for (int jj = 0; jj < 4; jj++) acc[i][jj] = zero4;

    for (int k0 = 0; k0 < DM; k0 += 32) {
        async16(ldsA0, gA0);
        async16(ldsA1, gA1);
        async16(ldsB0, gB0);
        async16(ldsB1, gB1);
        gA0 += 64; gA1 += 64; gB0 += 64; gB1 += 64;
        __syncthreads();

        bfrag a[4], bb[4];
        #pragma unroll
        for (int rt = 0; rt < 4; rt++) a[rt]  = *(const bfrag*)&sA[offA[rt]];
        #pragma unroll
        for (int ct = 0; ct < 4; ct++) bb[ct] = *(const bfrag*)&sB[offB[ct]];

        #pragma unroll
        for (int rt = 0; rt < 4; rt++)
            #pragma unroll
            for (int ct = 0; ct < 4; ct++)
                acc[rt][ct] = mfma16(a[rt], bb[ct], acc[rt][ct]);
        __syncthreads();
    }

    const float SCALE = (z == 0) ? 0.18033688011112042f : 1.0f; // log2(e)/8
    #pragma unroll
    for (int rt = 0; rt < 4; rt++)
        #pragma unroll
        for (int ct = 0; ct < 4; ct++)
            #pragma unroll
            for (int reg = 0; reg < 4; reg++) {
                int r = m0 + wr * 64 + rt * 16 + q4 * 4 + reg;
                int c = n0 + wc * 64 + ct * 16 + m16;
                float v = (acc[rt][ct][reg] + bias[c]) * SCALE;
                int s = r >> 1, b = r & 1, hh = c >> 6, d = c & 63;
                unsigned short bv16 = bf16_rn(v);
                if (z == 2)
                    outp[((size_t)(b * NH + hh) * HD + d) * S_LEN + s] = bv16;
                else
                    outp[((size_t)(b * NH + hh) * S_LEN + s) * HD + d] = bv16;
            }
}

// ---------------------------------------------------------------------------
// Attention, t-split x2 — EXACT R1 structure (proven 47.7 us, 0 conflicts,
// 64 VGPR, no spill). Ledger: setprio +15us (R4), frag-hoist spills (R3),
// t-split x4 thrashes L2 writes (R2). Local optimum; unchanged.
// ---------------------------------------------------------------------------
__global__ __launch_bounds__(256, 4)
void attn_kernel(const unsigned short* __restrict__ Qb,
                 const unsigned short* __restrict__ Kb,
                 const unsigned short* __restrict__ Vt,
                 unsigned short* __restrict__ Op,   // [2][BATCH*NH][S][HD] bf16
                 float* __restrict__ Lp)            // [2][BATCH*NH*S] fp32
{
    __shared__ unsigned short sK[2][64*64];    // 2 x 8 KB, XOR-swizzled rows
    __shared__ unsigned short sV[2][64*64];    // 2 x 8 KB

    const int tid = threadIdx.x, lane = tid & 63, w4 = tid >> 6;
    const int m16 = lane & 15, q4 = lane >> 4;

    int id = blockIdx.x;                 // 0..1023
    int xcd = id & 7, j = id >> 3;       // j 0..127
    const int bh   = xcd * 4 + (j >> 5); // 4 heads per XCD
    const int rem  = j & 31;
    const int half = rem & 1;            // t-range half
    const int qc   = rem >> 1;           // 0..15
    const int qw   = qc * 128 + w4 * 32;
    const int tbase = half * (S_LEN / 2);

    const unsigned short* Qp = Qb + (size_t)bh * (S_LEN * HD);
    const unsigned short* Kp = Kb + (size_t)bh * (S_LEN * HD);
    const unsigned short* Vp = Vt + (size_t)bh * (S_LEN * HD);

    // Q B-fragments (fixed for whole kernel): [n=q=lane&15][k=d]
    bfrag aq[2][2];
    #pragma unroll
    for (int nt = 0; nt < 2; nt++)
        #pragma unroll
        for (int kc = 0; kc < 2; kc++)
            aq[nt][kc] = *(const bfrag*)&Qp[(size_t)(qw + nt*16 + m16) * HD + kc*32 + q4*8];

    // staging: 512 granules (16B) per matrix, 2 async16 per thread per matrix.
    const int r0 = tid >> 3,         g0 = (tid & 7) ^ (r0 & 7);
    const int r1 = (tid + 256) >> 3, g1 = (tid & 7) ^ (r1 & 7);
    const char* gK0 = (const char*)Kp + (size_t)(tbase + r0) * 128 + g0 * 16;
    const char* gK1 = (const char*)Kp + (size_t)(tbase + r1) * 128 + g1 * 16;
    const char* gV0 = (const char*)Vp + (size_t)r0 * 4096 + tbase * 2 + g0 * 16;
    const char* gV1 = (const char*)Vp + (size_t)r1 * 4096 + tbase * 2 + g1 * 16;
    const int ldsw = w4 * 1024;

    const f32x4 zero4 = {0.f, 0.f, 0.f, 0.f};
    f32x4 O[2][4];
    float lp[2] = {0.f, 0.f};
    #pragma unroll
    for (int nt = 0; nt < 2; nt++)
        #pragma unroll
        for (int dt = 0; dt < 4; dt++) O[nt][dt] = zero4;

    // prefetch tile 0 into buffer 0
    async16((char*)sK[0] + ldsw,        gK0);
    async16((char*)sK[0] + 4096 + ldsw, gK1);
    async16((char*)sV[0] + ldsw,        gV0);
    async16((char*)sV[0] + 4096 + ldsw, gV1);

    const int NT = (S_LEN / 2) / 64;     // 16 tiles per half
    for (int it = 0; it < NT; it++) {
        const int bi = it & 1;
        __syncthreads();   // drains async (cur tile ready) + prior compute done
        if (it + 1 < NT) {
            size_t ko = (size_t)(it + 1) * 8192, vo = (size_t)(it + 1) * 128;
            async16((char*)sK[bi^1] + ldsw,        gK0 + ko);
            async16((char*)sK[bi^1] + 4096 + ldsw, gK1 + ko);
            async16((char*)sV[bi^1] + ldsw,        gV0 + vo);
            async16((char*)sV[bi^1] + 4096 + ldsw, gV1 + vo);
        }

        const unsigned short* kb = sK[bi];
        const unsigned short* vb = sV[bi];

        // K A-frags [m=t][k=d] from swizzled LDS
        bfrag ak[4][2];
        #pragma unroll
        for (int mt = 0; mt < 4; mt++) {
            int r = mt*16 + m16, s = r & 7;
            ak[mt][0] = *(const bfrag*)&kb[r*64 + ((q4     ^ s) << 3)];
            ak[mt][1] = *(const bfrag*)&kb[r*64 + (((4+q4) ^ s) << 3)];
        }

        // S^T = K.Q^T; p = exp2(s); cvt_pk to bf16 pairs; permlane-swap into
        // PV B-frags entirely in-register. l from raw p (additive).
        bfrag bpv[2][2];
        #pragma unroll
        for (int nt = 0; nt < 2; nt++) {
            f32x4 Sc[4];
            #pragma unroll
            for (int mt = 0; mt < 4; mt++) {
                Sc[mt] = mfma16(ak[mt][0], aq[nt][0], zero4);
                Sc[mt] = mfma16(ak[mt][1], aq[nt][1], Sc[mt]);
            }
            unsigned u0[4], u1[4];
            #pragma unroll
            for (int mt = 0; mt < 4; mt++) {
                float p0 = EXP2F(Sc[mt][0]), p1 = EXP2F(Sc[mt][1]);
                float p2 = EXP2F(Sc[mt][2]), p3 = EXP2F(Sc[mt][3]);
                lp[nt] += (p0 + p1) + (p2 + p3);
                u0[mt] = cvtpk_bf16(p0, p1);   // t = base+{0,1}
                u1[mt] = cvtpk_bf16(p2, p3);   // t = base+{2,3}
            }
            #pragma unroll
            for (int kc = 0; kc < 2; kc++) {
                unsigned a0 = u0[2*kc], b0 = u0[2*kc+1];
                pl32swap(a0, b0);              // bit5 exchange (tile select)
                pl16swap(a0, b0);              // bit4 exchange -> a0: j2=0, b0: j2=2
                unsigned a1 = u1[2*kc], b1 = u1[2*kc+1];
                pl32swap(a1, b1);
                pl16swap(a1, b1);              // a1: j2=1, b1: j2=3
                i32x4_t w = { (int)a0, (int)a1, (int)b0, (int)b1 };
                bpv[nt][kc] = __builtin_bit_cast(bfrag, w);
            }
        }

        // V^T A-frags [m=d][k=t] from swizzled LDS
        bfrag av[4][2];
        #pragma unroll
        for (int dt = 0; dt < 4; dt++) {
            int r = dt*16 + m16, s = r & 7;
            av[dt][0] = *(const bfrag*)&vb[r*64 + ((q4     ^ s) << 3)];
            av[dt][1] = *(const bfrag*)&vb[r*64 + (((4+q4) ^ s) << 3)];
        }

        // O^T += V^T . P^T  (P^T B-frags in registers)
        #pragma unroll
        for (int nt = 0; nt < 2; nt++)
            #pragma unroll
            for (int dt = 0; dt < 4; dt++) {
                O[nt][dt] = mfma16(av[dt][0], bpv[nt][0], O[nt][dt]);
                O[nt][dt] = mfma16(av[dt][1], bpv[nt][1], O[nt][dt]);
            }
    }

    // epilogue: reduce l over quads, write UNNORMALIZED bf16 O partial + l
    const size_t OPH = (size_t)BATCH * NH * S_LEN * HD;  // 4,194,304 elems
    unsigned short* Ob = Op + (size_t)half * OPH;
    float* Lb = Lp + (size_t)half * (BATCH * NH * S_LEN);
    #pragma unroll
    for (int nt = 0; nt < 2; nt++) {
        float l = lp[nt];
        l += __shfl_xor(l, 16);
        l += __shfl_xor(l, 32);
        int q = qw + nt*16 + m16;
        if (q4 == 0) Lb[(size_t)bh * S_LEN + q] = l;
        size_t rb = ((size_t)bh * S_LEN + q) * HD;
        #pragma unroll
        for (int dt = 0; dt < 4; dt++) {
            u16x4_t o = { bf16_rn(O[nt][dt][0]), bf16_rn(O[nt][dt][1]),
                          bf16_rn(O[nt][dt][2]), bf16_rn(O[nt][dt][3]) };
            *(u16x4_t*)&Ob[rb + dt*16 + q4*4] = o;
        }
    }
}

// ---------------------------------------------------------------------------
// Combine the two t-half partials: Ap = bf16((O0+O1)/(l0+l1)), laid out as
// the out-projection A-plane [r = s*2+b][h*64+d]. RESTORED as separate kernel:
// R7 proved fusing it into out_gemm costs +13us (serial reg-staging, ds_write
// conflicts, combine redone x16) while launch-count reduction saves ~0
// (fixed ~70us overhead is per-invocation, not per-launch).
// ---------------------------------------------------------------------------
__global__ __launch_bounds__(256)
void cmb_kernel(const unsigned short* __restrict__ Op,
                const float* __restrict__ Lp,
                unsigned short* __restrict__ Ap)
{
    const size_t OPH = (size_t)BATCH * NH * S_LEN * HD;
    int idx = blockIdx.x * 256 + threadIdx.x;     // 524288 threads x 8 elems
    int rho = idx >> 3, dg = idx & 7;             // rho = bh*2048 + q
    size_t e = (size_t)rho * HD + dg * 8;
    float inv = 1.0f / (Lp[rho] + Lp[BATCH*NH*S_LEN + rho]);
    u16x8_t a = *(const u16x8_t*)&Op[e];
    u16x8_t b2 = *(const u16x8_t*)&Op[OPH + e];
    u16x8_t r;
    #pragma unroll
    for (int i = 0; i < 8; i++) {
        float fa = __builtin_bit_cast(float, (unsigned)(unsigned short)a[i]  << 16);
        float fb = __builtin_bit_cast(float, (unsigned)(unsigned short)b2[i] << 16);
        r[i] = bf16_rn((fa + fb) * inv);
    }
    int bh = rho >> 11, q = rho & 2047;
    int b = bh >> 4, h = bh & 15;
    *(u16x8_t*)&Ap[((size_t)(q * 2 + b)) * DM + h * 64 + dg * 8] = r;
}

// ---------------------------------------------------------------------------
// Out projection: d_out = attn @ Wo^T + bo (fp32), 2-phase W split.
// R8: BK=64 (R5's verified variant). R1-vs-R5 A/B isolated out_gemm's BK64
// delta to ~-9us: at 2 blocks/CU (512-block grid) too few waves hide the
// per-barrier drain, so halving barrier count wins here (unlike qkv at 3).
// ---------------------------------------------------------------------------
__global__ __launch_bounds__(256)
void out_gemm(const unsigned short* __restrict__ Ap,
              const unsigned short* __restrict__ Woh,
              const unsigned short* __restrict__ Wol,
              const float* __restrict__ bo, float* __restrict__ out)
{
    __shared__ unsigned short sA[128*64];   // 16 KB = 2 x 8KB sub-tiles
    __shared__ unsigned short sH[64*64];    // 8 KB  = 2 x 4KB sub-tiles
    __shared__ unsigned short sL[64*64];    // 8 KB

    const int tid = threadIdx.x, lane = tid & 63, w4 = tid >> 6;
    const int m16 = lane & 15, q4 = lane >> 4;
    const int wr = w4 >> 1, wc = w4 & 1;    // 2x2 -> 64 M x 32 N per wave

    int id = blockIdx.x + 16 * blockIdx.y;  // 512 blocks
    int j  = id >> 3;                        // 0..63
    const int m0 = ((id & 7) * 4 + (j & 3)) * 128;
    const int n0 = (j >> 2) * 64;

    // A staging: 512 granules, 2/thread; H/L: 256 granules, 1/thread each
    const int G1 = tid + 256;
    const int r0 = tid >> 2, g0 = (tid & 3) ^ ((r0 ^ (r0 >> 2)) & 3);
    const int r1 = G1  >> 2, g1 = (G1  & 3) ^ ((r1 ^ (r1 >> 2)) & 3);
    const char* gA0 = (const char*)Ap  + (size_t)(m0 + r0) * 2048 + g0 * 16;
    const char* gA1 = (const char*)Ap  + (size_t)(m0 + r1) * 2048 + g1 * 16;
    const char* gH  = (const char*)Woh + (size_t)(n0 + r0) * 2048 + g0 * 16;
    const char* gL  = (const char*)Wol + (size_t)(n0 + r0) * 2048 + g0 * 16;
    char* ldsA0 = (char*)sA + w4 * 1024;
    char* ldsA1 = (char*)sA + 4096 + w4 * 1024;
    char* ldsH  = (char*)sH + w4 * 1024;
    char* ldsL  = (char*)sL + w4 * 1024;

    int offA[4], offB[2];
    #pragma unroll
    for (int rt = 0; rt < 4; rt++) {
        int r = wr * 64 + rt * 16 + m16;
        offA[rt] = r * 32 + ((q4 ^ ((r ^ (r >> 2)) & 3)) << 3);
    }
    #pragma unroll
    for (int ct = 0; ct < 2; ct++) {
        int r = wc * 32 + ct * 16 + m16;
        offB[ct] = r * 32 + ((q4 ^ ((r ^ (r >> 2)) & 3)) << 3);
    }

    f32x4 acc[4][2];
    const f32x4 zero4 = {0.f, 0.f, 0.f, 0.f};
    #pragma unroll
    for (int i = 0; i < 4; i++)
        #pragma unroll
        for (int jj = 0; jj < 2; jj++) acc[i][jj] = zero4;

    for (int k0 = 0; k0 < DM; k0 += 64) {
        async16(ldsA0, gA0);
        async16(ldsA1, gA1);
        async16(ldsH,  gH);
        async16(ldsL,  gL);
        async16(ldsA0 + 8192, gA0 + 64);
        async16(ldsA1 + 8192, gA1 + 64);
        async16(ldsH  + 4096, gH  + 64);
        async16(ldsL  + 4096, gL  + 64);
        gA0 += 128; gA1 += 128; gH += 128; gL += 128;
        __syncthreads();

        #pragma unroll
        for (int sub = 0; sub < 2; sub++) {
            const int soA = sub * 4096;    // elements (8 KB)
            const int soB = sub * 2048;    // elements (4 KB)
            bfrag a[4], bh2[2], bl2[2];
            #pragma unroll
            for (int rt = 0; rt < 4; rt++) a[rt] = *(const bfrag*)&sA[soA + offA[rt]];
            #pragma unroll
            for (int ct = 0; ct < 2; ct++) {
                bh2[ct] = *(const bfrag*)&sH[soB + offB[ct]];
                bl2[ct] = *(const bfrag*)&sL[soB + offB[ct]];
            }
            #pragma unroll
            for (int rt = 0; rt < 4; rt++)
                #pragma unroll
                for (int ct = 0; ct < 2; ct++) {
                    acc[rt][ct] = mfma16(a[rt], bh2[ct], acc[rt][ct]);
                    acc[rt][ct] = mfma16(a[rt], bl2[ct], acc[rt][ct]);
                }
        }
        __syncthreads();
    }

    #pragma unroll
    for (int rt = 0; rt < 4; rt++)
        #pragma unroll
        for (int ct = 0; ct < 2; ct++)
            #pragma unroll
            for (int reg = 0; reg < 4; reg++) {
                int r = m0 + wr * 64 + rt * 16 + q4 * 4 + reg;
                int c = n0 + wc * 32 + ct * 16 + m16;
                out[(size_t)r * DM + c] = acc[rt][ct][reg] + bo[c];
            }
}

// ---------------------------------------------------------------------------
extern "C" void kernel_launch(void* const* d_in, const int* in_sizes, int n_in,
                              void* d_out, int out_size, void* d_ws, size_t ws_size,
                              hipStream_t stream)
{
    const float* query = (const float*)d_in[0];
    const float* key   = (const float*)d_in[1];
    const float* value = (const float*)d_in[2];
    const float* Wq    = (const float*)d_in[3];
    const float* bq    = (const float*)d_in[4];
    const float* Wk    = (const float*)d_in[5];
    const float* bk    = (const float*)d_in[6];
    const float* Wv    = (const float*)d_in[7];
    const float* bv    = (const float*)d_in[8];
    const float* Wo    = (const float*)d_in[9];
    const float* bo    = (const float*)d_in[10];

    char* ws = (char*)d_ws;
    const size_t MB = 1u << 20;
    unsigned short* Qb  = (unsigned short*)(ws);            //  0..8 MB
    unsigned short* Kb  = (unsigned short*)(ws +  8*MB);    //  8..16
    unsigned short* Vt  = (unsigned short*)(ws + 16*MB);    // 16..24
    unsigned short* Woh = (unsigned short*)(ws + 24*MB);    // 24..26 (live till out)
    unsigned short* Wol = (unsigned short*)(ws + 26*MB);    // 26..28
    unsigned short* Wqb = (unsigned short*)(ws + 28*MB);    // 28..30 (dead after qkv)
    unsigned short* Wkb = (unsigned short*)(ws + 30*MB);    // 30..32 (dead after qkv)
    unsigned short* Wvb = (unsigned short*)(ws + 32*MB);    // 32..34 (dead after qkv)
    unsigned short* Va  = (unsigned short*)(ws + 34*MB);    // 34..42 (dead after qkv)
    float*          Lp  = (float*)         (ws + 28*MB);    // 28..28.5 (attn l partials,
                                                            //   over dead Wqb)
    unsigned short* Apl = (unsigned short*)(ws + 34*MB);    // 34..42 (combined A-plane,
                                                            //   over dead Va)
    // O partials (2 x 8 MB bf16) live in d_out (free between qkv and out_gemm).
    unsigned short* Opart = (unsigned short*)d_out;
    // Qa/Ka bf16 A-planes also live in d_out during cvt+qkv.
    unsigned short* Qa  = (unsigned short*)d_out;                    // d_out 0..8 MB
    unsigned short* Ka  = (unsigned short*)d_out + (size_t)MROWS*DM; // 8..16 MB
    // peak ws footprint: 42 MB

    cvt_kernel<<<dim3(2048, 1, 7), 256, 0, stream>>>(
        Wq, Wk, Wv, Wo, query, key, value,
        Wqb, Wkb, Wvb, Woh, Wol, Qa, Ka, Va);
    qkv_gemm<<<dim3(8, 32, 3), 256, 0, stream>>>(
        Qa, Ka, Va, Wqb, Wkb, Wvb, bq, bk, bv, Qb, Kb, Vt);
    attn_kernel<<<dim3(1024), 256, 0, stream>>>(Qb, Kb, Vt, Opart, Lp);
    cmb_kernel<<<dim3(2048), 256, 0, stream>>>(Opart, Lp, Apl);
    out_gemm<<<dim3(16, 32), 256, 0, stream>>>(Apl, Woh, Wol, bo, (float*)d_out);
}